// Round 9
// baseline (439.854 us; speedup 1.0000x reference)
//
#include <hip/hip_runtime.h>
#include <math.h>

// Problem constants: B=8, C=64 (HC=32), H=W=256.
// Outputs (concat, fp32): score[8*65536] | out[8*65536*5] | m[8*65536]
// hmap (vertical conv) in the reference is dead code (bf[:,:,2] never used).
//
// R8: single kernel = R7's verified phase-1 structure (good occupancy) +
// R5's verified atomic last-block sync (correct on HW; its 186us was an
// occupancy failure, not a sync failure). 1024 blocks x 256 thr,
// __launch_bounds__(256,4): 4 blocks/CU x 256 CU = ALL 1024 co-resident
// (VGPR<=128 forced, LDS 12.3KB <= 40KB) -> spin-wait is deadlock-free by
// construction. Each block: 2 rows phase-1, publish top-10, ticket; last of
// the batch's 128 blocks merges 128 lists -> tvals[b] -> flag; all blocks
// spin then run the boxes epilogue from LDS-resident s/m. Removes k_boxes'
// 2048-block pass, its 4MiB re-read, 2048 redundant merges, one boundary.

// Sorted-descending merge of a[NA] and b[NB] -> a[min(NA+NB,10)].
template<int NA, int NB>
__device__ __forceinline__ void merge_sz(float (&a)[10], const float (&b)[10]) {
    constexpr int NC = (NA + NB < 10) ? (NA + NB) : 10;
    float c[10];
#pragma unroll
    for (int k = 0; k < NC; ++k) {
        float best = (k < NA) ? a[k] : -INFINITY;
        if (k < NB) best = fmaxf(best, b[k]);
#pragma unroll
        for (int i = 0; i < NA; ++i) {
            const int j = k - 1 - i;
            if (j >= 0 && j < NB) best = fmaxf(best, fminf(a[i], b[j]));
        }
        c[k] = best;
    }
#pragma unroll
    for (int k = 0; k < NC; ++k) a[k] = c[k];
}

// Wave-wide top-10 of one value per lane (sorted descending in t).
// Size-aware butterfly: lists grow 1,2,4,8,10 -> ~330 VALU vs 660 full-width.
__device__ __forceinline__ void wave_top10(float s, float (&t)[10]) {
    t[0] = s;
#pragma unroll
    for (int k = 1; k < 10; ++k) t[k] = -INFINITY;
    float bt[10];
#pragma unroll
    for (int k = 0; k < 10; ++k) bt[k] = -INFINITY;

    bt[0] = __shfl_xor(t[0], 1);
    merge_sz<1, 1>(t, bt);
#pragma unroll
    for (int k = 0; k < 2; ++k) bt[k] = __shfl_xor(t[k], 2);
    merge_sz<2, 2>(t, bt);
#pragma unroll
    for (int k = 0; k < 4; ++k) bt[k] = __shfl_xor(t[k], 4);
    merge_sz<4, 4>(t, bt);
#pragma unroll
    for (int k = 0; k < 8; ++k) bt[k] = __shfl_xor(t[k], 8);
    merge_sz<8, 8>(t, bt);
#pragma unroll
    for (int k = 0; k < 10; ++k) bt[k] = __shfl_xor(t[k], 16);
    merge_sz<10, 10>(t, bt);
#pragma unroll
    for (int k = 0; k < 10; ++k) bt[k] = __shfl_xor(t[k], 32);
    merge_sz<10, 10>(t, bt);
}

__global__ __launch_bounds__(256, 4) void k_all(
    const float* __restrict__ color,
    const float* __restrict__ w_bbx,
    const float* __restrict__ w_width,
    const float* __restrict__ w_score,
    float* __restrict__ score_out,
    float* __restrict__ out5,
    float* __restrict__ mout,
    int*   __restrict__ cnt,     // ws [8], zeroed by memset
    int*   __restrict__ flag,    // ws [8], zeroed by memset
    float* __restrict__ tvals,   // ws [8]
    float* __restrict__ lists)   // ws [1024][10]
{
    const int tid  = threadIdx.x;
    const int lane = tid & 63;
    const int wid  = tid >> 6;              // 0..3: channel group (wave-uniform)
    const int bid  = blockIdx.x;            // 0..1023
    const int b    = bid >> 7;              // batch (128 blocks per batch)
    const int rg   = bid & 127;             // rows 2*rg, 2*rg+1
    const int w0   = lane << 2;             // 0..252

    const int cg = __builtin_amdgcn_readfirstlane(wid) << 4;  // 0,16,32,48

    __shared__ float sa[4][256];
    __shared__ float sm[4][256];
    __shared__ float sfin[2][256];  // persists to epilogue
    __shared__ float mfin[2][256];  // persists to epilogue
    __shared__ float wl[4][10];
    __shared__ int   last_s;
    __shared__ float tb_s;

    float run10[10];

    // ---------------- Phase 1: 2 rows of score + wmap + top-10 ----------------
    for (int r = 0; r < 2; ++r) {
        const int h = (rg << 1) + r;
        const float* base = color + ((size_t)b << 22) + ((size_t)h << 8) + (size_t)w0
                                  + ((size_t)cg << 16);

        float4 vv[16];
#pragma unroll
        for (int j = 0; j < 16; ++j)
            vv[j] = *reinterpret_cast<const float4*>(base + ((size_t)j << 16));

        float a0 = 0.f, a1 = 0.f, a2 = 0.f, a3 = 0.f;
        float m0 = -INFINITY, m1 = -INFINITY, m2 = -INFINITY, m3 = -INFINITY;

#pragma unroll
        for (int j = 0; j < 16; j += 2) {
            const float4 v = vv[j];
            const float4 u = vv[j + 1];
            const int c = cg + j;
            const float wsc0 = w_score[c];
            const float wsc1 = w_score[c + 1];
            a0 += v.x * wsc0 + u.x * wsc1;
            a1 += v.y * wsc0 + u.y * wsc1;
            a2 += v.z * wsc0 + u.z * wsc1;
            a3 += v.w * wsc0 + u.w * wsc1;

            const float wb = w_bbx[c];
            const float ex = v.x * wb, ey = v.y * wb, ez = v.z * wb, ew = v.w * wb;
            float lm2 = __shfl_up(ez, 1);    // pixel w0-2
            float lm1 = __shfl_up(ew, 1);    // pixel w0-1
            float rp1 = __shfl_down(ex, 1);  // pixel w0+4
            float rp2 = __shfl_down(ey, 1);  // pixel w0+5
            if (lane == 0)  { lm2 = 0.f; lm1 = 0.f; }   // zero padding (left)
            if (lane == 63) { rp1 = 0.f; rp2 = 0.f; }   // zero padding (right)

            const int hc = c >> 1;
            const float t0 = w_width[hc * 5 + 0];
            const float t1 = w_width[hc * 5 + 1];
            const float t2 = w_width[hc * 5 + 2];
            const float t3 = w_width[hc * 5 + 3];
            const float t4 = w_width[hc * 5 + 4];

            m0 = fmaxf(m0, lm2 * t0 + lm1 * t1 + ex * t2 + ey * t3 + ez * t4);
            m1 = fmaxf(m1, lm1 * t0 + ex * t1 + ey * t2 + ez * t3 + ew * t4);
            m2 = fmaxf(m2, ex * t0 + ey * t1 + ez * t2 + ew * t3 + rp1 * t4);
            m3 = fmaxf(m3, ey * t0 + ez * t1 + ew * t2 + rp1 * t3 + rp2 * t4);
        }

        if (r) __syncthreads();  // protect sa/sm reuse (write-after-read)
        *reinterpret_cast<float4*>(&sa[wid][w0]) = make_float4(a0, a1, a2, a3);
        *reinterpret_cast<float4*>(&sm[wid][w0]) = make_float4(m0, m1, m2, m3);
        __syncthreads();

        const float s = (sa[0][tid] + sa[1][tid]) + (sa[2][tid] + sa[3][tid]);
        const float m = fmaxf(fmaxf(sm[0][tid], sm[1][tid]), fmaxf(sm[2][tid], sm[3][tid]));
        sfin[r][tid] = s;
        mfin[r][tid] = m;
        score_out[((size_t)b << 16) + ((size_t)h << 8) + (size_t)tid] = s;

        float t10[10];
        wave_top10(s, t10);
        if (r == 0) {
#pragma unroll
            for (int k = 0; k < 10; ++k) run10[k] = t10[k];
        } else {
            merge_sz<10, 10>(run10, t10);
        }
    }

    if (lane == 0) {
#pragma unroll
        for (int k = 0; k < 10; ++k) wl[wid][k] = run10[k];
    }
    __syncthreads();

    // ---------------- publish this block's list + ticket ----------------
    if (tid == 0) {
        float fa[10], fb[10];
#pragma unroll
        for (int k = 0; k < 10; ++k) fa[k] = wl[0][k];
#pragma unroll
        for (int k = 0; k < 10; ++k) fb[k] = wl[1][k];
        merge_sz<10, 10>(fa, fb);
#pragma unroll
        for (int k = 0; k < 10; ++k) fb[k] = wl[2][k];
        merge_sz<10, 10>(fa, fb);
#pragma unroll
        for (int k = 0; k < 10; ++k) fb[k] = wl[3][k];
        merge_sz<10, 10>(fa, fb);
#pragma unroll
        for (int k = 0; k < 10; ++k) lists[bid * 10 + k] = fa[k];

        __threadfence();  // make lists visible device-wide before the ticket
        const int ticket = __hip_atomic_fetch_add(&cnt[b], 1, __ATOMIC_ACQ_REL,
                                                  __HIP_MEMORY_SCOPE_AGENT);
        last_s = (ticket == 127) ? 1 : 0;
    }
    __syncthreads();

    // ------- last block of the batch: merge 128 lists -> tvals[b] -------
    if (last_s && wid == 0) {
        __threadfence();  // acquire: other blocks' lists
        const float* p = lists + ((size_t)b << 7) * 10;
        float a[10], t[10];
#pragma unroll
        for (int k = 0; k < 10; ++k) a[k] = p[lane * 10 + k];
#pragma unroll
        for (int k = 0; k < 10; ++k) t[k] = p[(lane + 64) * 10 + k];
        merge_sz<10, 10>(a, t);
        float bt[10];
#pragma unroll
        for (int off = 1; off < 64; off <<= 1) {
#pragma unroll
            for (int k = 0; k < 10; ++k) bt[k] = __shfl_xor(a[k], off);
            merge_sz<10, 10>(a, bt);
        }
        if (lane == 0) {
            tvals[b] = a[9];
            __threadfence();
            __hip_atomic_store(&flag[b], 1, __ATOMIC_RELEASE, __HIP_MEMORY_SCOPE_AGENT);
        }
    }

    // ---------------- wait for the batch threshold ----------------
    if (tid == 0) {
        while (__hip_atomic_load(&flag[b], __ATOMIC_ACQUIRE,
                                 __HIP_MEMORY_SCOPE_AGENT) == 0) {
            __builtin_amdgcn_s_sleep(4);
        }
        __threadfence();
        tb_s = tvals[b];
    }
    __syncthreads();
    const float tb = tb_s;

    // ---------------- epilogue: boxes from LDS-resident s/m ----------------
    for (int r = 0; r < 2; ++r) {
        const int h  = (rg << 1) + r;
        const int i  = (b << 16) | (h << 8) | tid;
        const float sc = sfin[r][tid];
        const float wm = mfin[r][tid];

        const double sd = 1.0 / (1.0 + exp(-(double)sc));
        const bool top  = (sc >= tb);  // monotone: top-10 of sigmoid == top-10 of score
        const bool m    = (top && (sd > 0.6)) || (sd > 0.8);

        const double xg = (double)(i & 255);
        const double yg = (double)((i >> 8) & 255);
        const double cw = exp((double)sc) * 10.0;  // wv = bf[:,:,0] = score
        const double ch = exp((double)wm) * 10.0;  // hv = bf[:,:,1] = wmap

        double x1 = floor(xg - cw), x2 = ceil(xg + cw);
        double y1 = floor(yg - ch), y2 = ceil(yg + ch);
        if ((x1 < 0.0) || (x2 > 256.0)) {
            const double hw = fmin(256.0 - xg, xg);
            x1 = floor(xg - hw); x2 = ceil(xg + hw);
        }
        if ((y1 < 0.0) || (y2 > 256.0)) {
            const double hh = fmin(256.0 - yg, yg);
            y1 = floor(yg - hh); y2 = ceil(yg + hh);
        }

        const float mf = m ? 1.0f : 0.0f;
        const size_t o = (size_t)i * 5;
        out5[o + 0] = mf * (float)sd;
        out5[o + 1] = mf * (float)x1;
        out5[o + 2] = mf * (float)y1;
        out5[o + 3] = mf * (float)x2;
        out5[o + 4] = mf * (float)y2;
        mout[i] = mf;
    }
}

extern "C" void kernel_launch(void* const* d_in, const int* in_sizes, int n_in,
                              void* d_out, int out_size, void* d_ws, size_t ws_size,
                              hipStream_t stream) {
    // inputs: 0=mask(unused), 1=color, 2=w_bbx, 3=w_width, 4=w_height(dead), 5=w_score
    const float* color   = (const float*)d_in[1];
    const float* w_bbx   = (const float*)d_in[2];
    const float* w_width = (const float*)d_in[3];
    const float* w_score = (const float*)d_in[5];

    float* score_out = (float*)d_out;                       // 524288
    float* out5      = score_out + 524288;                  // 2621440
    float* mout      = score_out + 524288 + 2621440;        // 524288

    // ws layout: [cnt 8 int][flag 8 int][tvals 8 f][lists 10240 f]
    int*   cnt   = (int*)d_ws;
    int*   flagp = cnt + 8;
    float* tvals = (float*)(flagp + 8);
    float* lists = tvals + 8;

    // zero the sync counters (workspace is poisoned by the harness each iter)
    hipMemsetAsync(d_ws, 0, 64, stream);

    k_all<<<1024, 256, 0, stream>>>(color, w_bbx, w_width, w_score,
                                    score_out, out5, mout,
                                    cnt, flagp, tvals, lists);
}

// Round 11
// 241.595 us; speedup vs baseline: 1.8206x; 1.8206x over previous
//
#include <hip/hip_runtime.h>
#include <math.h>

// Problem constants: B=8, C=64 (HC=32), H=W=256.
// Outputs (concat, fp32): score[8*65536] | out[8*65536*5] | m[8*65536]
// hmap (vertical conv) in the reference is dead code (bf[:,:,2] never used).
//
// R9/R10: MEASUREMENT ROUND (resubmitted after infra failure). R7 config
// exactly, but k_main is launched TWICE (pure function of inputs ->
// idempotent; stream-serialized). Delta vs R7's 213.7us = T(k_main).
// Rationale: R8 proved intra-kernel spin sync poisons the memory system
// (agent-scope acquire polls: 310us @ 3.8% VALUBusy); 2-kernel design is
// the base. k_main's true duration is unknown (hidden below the 77us
// harness fills in rocprof top-5) and determines the next target:
// ~22us delta = at BW floor -> attack k_boxes/gaps; ~40us+ -> pipeline
// k_main's loads.

// Sorted-descending merge of a[NA] and b[NB] -> a[min(NA+NB,10)].
template<int NA, int NB>
__device__ __forceinline__ void merge_sz(float (&a)[10], const float (&b)[10]) {
    constexpr int NC = (NA + NB < 10) ? (NA + NB) : 10;
    float c[10];
#pragma unroll
    for (int k = 0; k < NC; ++k) {
        float best = (k < NA) ? a[k] : -INFINITY;
        if (k < NB) best = fmaxf(best, b[k]);
#pragma unroll
        for (int i = 0; i < NA; ++i) {
            const int j = k - 1 - i;
            if (j >= 0 && j < NB) best = fmaxf(best, fminf(a[i], b[j]));
        }
        c[k] = best;
    }
#pragma unroll
    for (int k = 0; k < NC; ++k) a[k] = c[k];
}

// Wave-wide top-10 of one value per lane (sorted descending in t).
// Size-aware butterfly: lists grow 1,2,4,8,10 -> ~330 VALU vs 660 full-width.
__device__ __forceinline__ void wave_top10(float s, float (&t)[10]) {
    t[0] = s;
#pragma unroll
    for (int k = 1; k < 10; ++k) t[k] = -INFINITY;
    float bt[10];
#pragma unroll
    for (int k = 0; k < 10; ++k) bt[k] = -INFINITY;

    bt[0] = __shfl_xor(t[0], 1);
    merge_sz<1, 1>(t, bt);
#pragma unroll
    for (int k = 0; k < 2; ++k) bt[k] = __shfl_xor(t[k], 2);
    merge_sz<2, 2>(t, bt);
#pragma unroll
    for (int k = 0; k < 4; ++k) bt[k] = __shfl_xor(t[k], 4);
    merge_sz<4, 4>(t, bt);
#pragma unroll
    for (int k = 0; k < 8; ++k) bt[k] = __shfl_xor(t[k], 8);
    merge_sz<8, 8>(t, bt);
#pragma unroll
    for (int k = 0; k < 10; ++k) bt[k] = __shfl_xor(t[k], 16);
    merge_sz<10, 10>(t, bt);
#pragma unroll
    for (int k = 0; k < 10; ++k) bt[k] = __shfl_xor(t[k], 32);
    merge_sz<10, 10>(t, bt);
}

// K1: fused score (64-ch dot) + wmap (5-tap horiz depthwise conv on even
// channels, max over 32 channels) + per-row top-10 of score.
// One block per image row; 4 waves x 16 channels; partials combined via LDS.
__global__ __launch_bounds__(256, 4) void k_main(
    const float* __restrict__ color,
    const float* __restrict__ w_bbx,
    const float* __restrict__ w_width,
    const float* __restrict__ w_score,
    float* __restrict__ score_out,
    float* __restrict__ wmap_out,
    float* __restrict__ lists)          // [2048][10] per-row sorted top-10
{
    const int tid  = threadIdx.x;
    const int lane = tid & 63;
    const int wid  = tid >> 6;              // 0..3: channel group (wave-uniform)
    const int bid  = blockIdx.x;            // 0..2047
    const int b    = bid >> 8;              // batch
    const int h    = bid & 255;             // row
    const int w0   = lane << 2;             // 0..252

    const int cg = __builtin_amdgcn_readfirstlane(wid) << 4;  // 0,16,32,48

    const float* base = color + ((size_t)b << 22) + ((size_t)h << 8) + (size_t)w0
                              + ((size_t)cg << 16);

    // ---- batch-load all 16 channels (16 outstanding float4 loads) ----
    float4 vv[16];
#pragma unroll
    for (int j = 0; j < 16; ++j)
        vv[j] = *reinterpret_cast<const float4*>(base + ((size_t)j << 16));

    float a0 = 0.f, a1 = 0.f, a2 = 0.f, a3 = 0.f;
    float m0 = -INFINITY, m1 = -INFINITY, m2 = -INFINITY, m3 = -INFINITY;

#pragma unroll
    for (int j = 0; j < 16; j += 2) {
        const float4 v = vv[j];
        const float4 u = vv[j + 1];
        const int c = cg + j;
        const float wsc0 = w_score[c];
        const float wsc1 = w_score[c + 1];
        a0 += v.x * wsc0 + u.x * wsc1;
        a1 += v.y * wsc0 + u.y * wsc1;
        a2 += v.z * wsc0 + u.z * wsc1;
        a3 += v.w * wsc0 + u.w * wsc1;

        const float wb = w_bbx[c];
        const float ex = v.x * wb, ey = v.y * wb, ez = v.z * wb, ew = v.w * wb;
        float lm2 = __shfl_up(ez, 1);    // pixel w0-2
        float lm1 = __shfl_up(ew, 1);    // pixel w0-1
        float rp1 = __shfl_down(ex, 1);  // pixel w0+4
        float rp2 = __shfl_down(ey, 1);  // pixel w0+5
        if (lane == 0)  { lm2 = 0.f; lm1 = 0.f; }   // zero padding (left)
        if (lane == 63) { rp1 = 0.f; rp2 = 0.f; }   // zero padding (right)

        const int hc = c >> 1;
        const float t0 = w_width[hc * 5 + 0];
        const float t1 = w_width[hc * 5 + 1];
        const float t2 = w_width[hc * 5 + 2];
        const float t3 = w_width[hc * 5 + 3];
        const float t4 = w_width[hc * 5 + 4];

        m0 = fmaxf(m0, lm2 * t0 + lm1 * t1 + ex * t2 + ey * t3 + ez * t4);
        m1 = fmaxf(m1, lm1 * t0 + ex * t1 + ey * t2 + ez * t3 + ew * t4);
        m2 = fmaxf(m2, ex * t0 + ey * t1 + ez * t2 + ew * t3 + rp1 * t4);
        m3 = fmaxf(m3, ey * t0 + ez * t1 + ew * t2 + rp1 * t3 + rp2 * t4);
    }

    // Combine the 4 waves' partials through LDS (8 KB).
    __shared__ float sa[4][256];
    __shared__ float sm[4][256];
    *reinterpret_cast<float4*>(&sa[wid][w0]) = make_float4(a0, a1, a2, a3);
    *reinterpret_cast<float4*>(&sm[wid][w0]) = make_float4(m0, m1, m2, m3);
    __syncthreads();

    // 256 threads -> 256 pixels of this row; coalesced stores.
    const float s = (sa[0][tid] + sa[1][tid]) + (sa[2][tid] + sa[3][tid]);
    const float m = fmaxf(fmaxf(sm[0][tid], sm[1][tid]), fmaxf(sm[2][tid], sm[3][tid]));
    const size_t o = ((size_t)b << 16) + ((size_t)h << 8) + (size_t)tid;
    score_out[o] = s;
    wmap_out[o]  = m;

    // ---- per-row top-10: wave butterfly, then LDS merge of the 4 waves ----
    float t10[10];
    wave_top10(s, t10);

    __shared__ float wl[4][10];
    if (lane == 0) {
#pragma unroll
        for (int k = 0; k < 10; ++k) wl[wid][k] = t10[k];
    }
    __syncthreads();

    if (tid == 0) {
        float fa[10], fb[10];
#pragma unroll
        for (int k = 0; k < 10; ++k) fa[k] = wl[0][k];
#pragma unroll
        for (int k = 0; k < 10; ++k) fb[k] = wl[1][k];
        merge_sz<10, 10>(fa, fb);
#pragma unroll
        for (int k = 0; k < 10; ++k) fb[k] = wl[2][k];
        merge_sz<10, 10>(fa, fb);
#pragma unroll
        for (int k = 0; k < 10; ++k) fb[k] = wl[3][k];
        merge_sz<10, 10>(fa, fb);
#pragma unroll
        for (int k = 0; k < 10; ++k) lists[bid * 10 + k] = fa[k];
    }
}

// K2: boxes epilogue with per-block redundant threshold computation.
__global__ __launch_bounds__(256) void k_boxes(
    const float* __restrict__ score,
    const float* __restrict__ lists,
    float* __restrict__ out5,
    float* __restrict__ mout)
{
    const int tid = threadIdx.x;
    const int i   = blockIdx.x * 256 + tid;  // < 524288
    const int b   = i >> 16;                 // uniform per block
    const int pix = i & 65535;

    // issue pixel loads early (independent of the threshold merge)
    const float sc = score[i];
    const float wm = mout[i];

    __shared__ float tbs;
    if (tid < 64) {
        const float* p = lists + ((size_t)b << 8) * 10;   // batch b's 256 lists
        float a[10];
#pragma unroll
        for (int k = 0; k < 10; ++k) a[k] = p[tid * 10 + k];
#pragma unroll
        for (int j = 1; j < 4; ++j) {
            float t[10];
#pragma unroll
            for (int k = 0; k < 10; ++k) t[k] = p[(tid + 64 * j) * 10 + k];
            merge_sz<10, 10>(a, t);
        }
#pragma unroll
        for (int off = 1; off < 64; off <<= 1) {
            float b10[10];
#pragma unroll
            for (int k = 0; k < 10; ++k) b10[k] = __shfl_xor(a[k], off);
            merge_sz<10, 10>(a, b10);
        }
        if (tid == 0) tbs = a[9];
    }
    __syncthreads();
    const float tb = tbs;

    const double sd  = 1.0 / (1.0 + exp(-(double)sc));
    const bool  top  = (sc >= tb);  // monotone: top-10 of sigmoid == top-10 of score
    const bool  m    = (top && (sd > 0.6)) || (sd > 0.8);

    const double xg = (double)(pix & 255);
    const double yg = (double)(pix >> 8);
    const double cw = exp((double)sc) * 10.0;  // wv = bf[:,:,0] = score
    const double ch = exp((double)wm) * 10.0;  // hv = bf[:,:,1] = wmap

    double x1 = floor(xg - cw), x2 = ceil(xg + cw);
    double y1 = floor(yg - ch), y2 = ceil(yg + ch);
    if ((x1 < 0.0) || (x2 > 256.0)) {
        const double hw = fmin(256.0 - xg, xg);
        x1 = floor(xg - hw); x2 = ceil(xg + hw);
    }
    if ((y1 < 0.0) || (y2 > 256.0)) {
        const double hh = fmin(256.0 - yg, yg);
        y1 = floor(yg - hh); y2 = ceil(yg + hh);
    }

    const float mf = m ? 1.0f : 0.0f;
    const size_t o = (size_t)i * 5;
    out5[o + 0] = mf * (float)sd;
    out5[o + 1] = mf * (float)x1;
    out5[o + 2] = mf * (float)y1;
    out5[o + 3] = mf * (float)x2;
    out5[o + 4] = mf * (float)y2;
    mout[i] = mf;
}

extern "C" void kernel_launch(void* const* d_in, const int* in_sizes, int n_in,
                              void* d_out, int out_size, void* d_ws, size_t ws_size,
                              hipStream_t stream) {
    // inputs: 0=mask(unused), 1=color, 2=w_bbx, 3=w_width, 4=w_height(dead), 5=w_score
    const float* color   = (const float*)d_in[1];
    const float* w_bbx   = (const float*)d_in[2];
    const float* w_width = (const float*)d_in[3];
    const float* w_score = (const float*)d_in[5];

    float* score_out = (float*)d_out;                       // 524288
    float* out5      = score_out + 524288;                  // 2621440
    float* mout      = score_out + 524288 + 2621440;        // 524288 (holds wmap between K1 and K2)

    float* lists = (float*)d_ws;   // 2048*10 floats

    // MEASUREMENT: k_main launched twice (idempotent). dur delta vs R7 = T(k_main).
    k_main <<<2048, 256, 0, stream>>>(color, w_bbx, w_width, w_score, score_out, mout, lists);
    k_main <<<2048, 256, 0, stream>>>(color, w_bbx, w_width, w_score, score_out, mout, lists);
    k_boxes<<<2048, 256, 0, stream>>>(score_out, lists, out5, mout);
}

// Round 12
// 213.138 us; speedup vs baseline: 2.0637x; 1.1335x over previous
//
#include <hip/hip_runtime.h>
#include <math.h>

// Problem constants: B=8, C=64 (HC=32), H=W=256.
// Outputs (concat, fp32): score[8*65536] | out[8*65536*5] | m[8*65536]
// hmap (vertical conv) in the reference is dead code (bf[:,:,2] never used).
//
// R11: k_main verified at ~26-28us by the R9/R10 double-launch probe
// (= ~5.0 TB/s effective on its 134MB stream, 80% of achievable) -> left
// unchanged. This round attacks k_boxes: (1) out5 stores were 5 scattered
// dword stores/thread (stride 20B); now staged in LDS and written as 320
// coalesced float4s per block; (2) wmap parked in workspace instead of the
// mout region (no RMW coupling). Accounting: fills ~155us (harness, fixed),
// k_main ~26, k_boxes ~8-10, gaps ~20-25. If this is neutral, roofline.

// Sorted-descending merge of a[NA] and b[NB] -> a[min(NA+NB,10)].
template<int NA, int NB>
__device__ __forceinline__ void merge_sz(float (&a)[10], const float (&b)[10]) {
    constexpr int NC = (NA + NB < 10) ? (NA + NB) : 10;
    float c[10];
#pragma unroll
    for (int k = 0; k < NC; ++k) {
        float best = (k < NA) ? a[k] : -INFINITY;
        if (k < NB) best = fmaxf(best, b[k]);
#pragma unroll
        for (int i = 0; i < NA; ++i) {
            const int j = k - 1 - i;
            if (j >= 0 && j < NB) best = fmaxf(best, fminf(a[i], b[j]));
        }
        c[k] = best;
    }
#pragma unroll
    for (int k = 0; k < NC; ++k) a[k] = c[k];
}

// Wave-wide top-10 of one value per lane (sorted descending in t).
// Size-aware butterfly: lists grow 1,2,4,8,10 -> ~330 VALU vs 660 full-width.
__device__ __forceinline__ void wave_top10(float s, float (&t)[10]) {
    t[0] = s;
#pragma unroll
    for (int k = 1; k < 10; ++k) t[k] = -INFINITY;
    float bt[10];
#pragma unroll
    for (int k = 0; k < 10; ++k) bt[k] = -INFINITY;

    bt[0] = __shfl_xor(t[0], 1);
    merge_sz<1, 1>(t, bt);
#pragma unroll
    for (int k = 0; k < 2; ++k) bt[k] = __shfl_xor(t[k], 2);
    merge_sz<2, 2>(t, bt);
#pragma unroll
    for (int k = 0; k < 4; ++k) bt[k] = __shfl_xor(t[k], 4);
    merge_sz<4, 4>(t, bt);
#pragma unroll
    for (int k = 0; k < 8; ++k) bt[k] = __shfl_xor(t[k], 8);
    merge_sz<8, 8>(t, bt);
#pragma unroll
    for (int k = 0; k < 10; ++k) bt[k] = __shfl_xor(t[k], 16);
    merge_sz<10, 10>(t, bt);
#pragma unroll
    for (int k = 0; k < 10; ++k) bt[k] = __shfl_xor(t[k], 32);
    merge_sz<10, 10>(t, bt);
}

// K1: fused score (64-ch dot) + wmap (5-tap horiz depthwise conv on even
// channels, max over 32 channels) + per-row top-10 of score.
// One block per image row; 4 waves x 16 channels; partials combined via LDS.
__global__ __launch_bounds__(256, 4) void k_main(
    const float* __restrict__ color,
    const float* __restrict__ w_bbx,
    const float* __restrict__ w_width,
    const float* __restrict__ w_score,
    float* __restrict__ score_out,
    float* __restrict__ wmap_out,
    float* __restrict__ lists)          // [2048][10] per-row sorted top-10
{
    const int tid  = threadIdx.x;
    const int lane = tid & 63;
    const int wid  = tid >> 6;              // 0..3: channel group (wave-uniform)
    const int bid  = blockIdx.x;            // 0..2047
    const int b    = bid >> 8;              // batch
    const int h    = bid & 255;             // row
    const int w0   = lane << 2;             // 0..252

    const int cg = __builtin_amdgcn_readfirstlane(wid) << 4;  // 0,16,32,48

    const float* base = color + ((size_t)b << 22) + ((size_t)h << 8) + (size_t)w0
                              + ((size_t)cg << 16);

    // ---- batch-load all 16 channels (16 outstanding float4 loads) ----
    float4 vv[16];
#pragma unroll
    for (int j = 0; j < 16; ++j)
        vv[j] = *reinterpret_cast<const float4*>(base + ((size_t)j << 16));

    float a0 = 0.f, a1 = 0.f, a2 = 0.f, a3 = 0.f;
    float m0 = -INFINITY, m1 = -INFINITY, m2 = -INFINITY, m3 = -INFINITY;

#pragma unroll
    for (int j = 0; j < 16; j += 2) {
        const float4 v = vv[j];
        const float4 u = vv[j + 1];
        const int c = cg + j;
        const float wsc0 = w_score[c];
        const float wsc1 = w_score[c + 1];
        a0 += v.x * wsc0 + u.x * wsc1;
        a1 += v.y * wsc0 + u.y * wsc1;
        a2 += v.z * wsc0 + u.z * wsc1;
        a3 += v.w * wsc0 + u.w * wsc1;

        const float wb = w_bbx[c];
        const float ex = v.x * wb, ey = v.y * wb, ez = v.z * wb, ew = v.w * wb;
        float lm2 = __shfl_up(ez, 1);    // pixel w0-2
        float lm1 = __shfl_up(ew, 1);    // pixel w0-1
        float rp1 = __shfl_down(ex, 1);  // pixel w0+4
        float rp2 = __shfl_down(ey, 1);  // pixel w0+5
        if (lane == 0)  { lm2 = 0.f; lm1 = 0.f; }   // zero padding (left)
        if (lane == 63) { rp1 = 0.f; rp2 = 0.f; }   // zero padding (right)

        const int hc = c >> 1;
        const float t0 = w_width[hc * 5 + 0];
        const float t1 = w_width[hc * 5 + 1];
        const float t2 = w_width[hc * 5 + 2];
        const float t3 = w_width[hc * 5 + 3];
        const float t4 = w_width[hc * 5 + 4];

        m0 = fmaxf(m0, lm2 * t0 + lm1 * t1 + ex * t2 + ey * t3 + ez * t4);
        m1 = fmaxf(m1, lm1 * t0 + ex * t1 + ey * t2 + ez * t3 + ew * t4);
        m2 = fmaxf(m2, ex * t0 + ey * t1 + ez * t2 + ew * t3 + rp1 * t4);
        m3 = fmaxf(m3, ey * t0 + ez * t1 + ew * t2 + rp1 * t3 + rp2 * t4);
    }

    // Combine the 4 waves' partials through LDS (8 KB).
    __shared__ float sa[4][256];
    __shared__ float sm[4][256];
    *reinterpret_cast<float4*>(&sa[wid][w0]) = make_float4(a0, a1, a2, a3);
    *reinterpret_cast<float4*>(&sm[wid][w0]) = make_float4(m0, m1, m2, m3);
    __syncthreads();

    // 256 threads -> 256 pixels of this row; coalesced stores.
    const float s = (sa[0][tid] + sa[1][tid]) + (sa[2][tid] + sa[3][tid]);
    const float m = fmaxf(fmaxf(sm[0][tid], sm[1][tid]), fmaxf(sm[2][tid], sm[3][tid]));
    const size_t o = ((size_t)b << 16) + ((size_t)h << 8) + (size_t)tid;
    score_out[o] = s;
    wmap_out[o]  = m;

    // ---- per-row top-10: wave butterfly, then LDS merge of the 4 waves ----
    float t10[10];
    wave_top10(s, t10);

    __shared__ float wl[4][10];
    if (lane == 0) {
#pragma unroll
        for (int k = 0; k < 10; ++k) wl[wid][k] = t10[k];
    }
    __syncthreads();

    if (tid == 0) {
        float fa[10], fb[10];
#pragma unroll
        for (int k = 0; k < 10; ++k) fa[k] = wl[0][k];
#pragma unroll
        for (int k = 0; k < 10; ++k) fb[k] = wl[1][k];
        merge_sz<10, 10>(fa, fb);
#pragma unroll
        for (int k = 0; k < 10; ++k) fb[k] = wl[2][k];
        merge_sz<10, 10>(fa, fb);
#pragma unroll
        for (int k = 0; k < 10; ++k) fb[k] = wl[3][k];
        merge_sz<10, 10>(fa, fb);
#pragma unroll
        for (int k = 0; k < 10; ++k) lists[bid * 10 + k] = fa[k];
    }
}

// K2: boxes epilogue. Per-block redundant threshold merge (wave 0), then all
// 256 threads compute boxes into LDS; the block's contiguous 5120B out5
// region is written as 320 coalesced float4 stores. fp64 math to match
// numpy rounding. Reads wmap from workspace (no RMW on mout).
__global__ __launch_bounds__(256) void k_boxes(
    const float* __restrict__ score,
    const float* __restrict__ wmap,
    const float* __restrict__ lists,
    float* __restrict__ out5,
    float* __restrict__ mout)
{
    const int tid = threadIdx.x;
    const int i   = blockIdx.x * 256 + tid;  // < 524288
    const int b   = i >> 16;                 // uniform per block
    const int pix = i & 65535;

    // issue pixel loads early (independent of the threshold merge)
    const float sc = score[i];
    const float wm = wmap[i];

    __shared__ float tbs;
    __shared__ float rec[1280];  // 256 records x 5 floats, contiguous
    if (tid < 64) {
        const float* p = lists + ((size_t)b << 8) * 10;   // batch b's 256 lists
        float a[10];
#pragma unroll
        for (int k = 0; k < 10; ++k) a[k] = p[tid * 10 + k];
#pragma unroll
        for (int j = 1; j < 4; ++j) {
            float t[10];
#pragma unroll
            for (int k = 0; k < 10; ++k) t[k] = p[(tid + 64 * j) * 10 + k];
            merge_sz<10, 10>(a, t);
        }
#pragma unroll
        for (int off = 1; off < 64; off <<= 1) {
            float b10[10];
#pragma unroll
            for (int k = 0; k < 10; ++k) b10[k] = __shfl_xor(a[k], off);
            merge_sz<10, 10>(a, b10);
        }
        if (tid == 0) tbs = a[9];
    }
    __syncthreads();
    const float tb = tbs;

    const double sd  = 1.0 / (1.0 + exp(-(double)sc));
    const bool  top  = (sc >= tb);  // monotone: top-10 of sigmoid == top-10 of score
    const bool  m    = (top && (sd > 0.6)) || (sd > 0.8);

    const double xg = (double)(pix & 255);
    const double yg = (double)(pix >> 8);
    const double cw = exp((double)sc) * 10.0;  // wv = bf[:,:,0] = score
    const double ch = exp((double)wm) * 10.0;  // hv = bf[:,:,1] = wmap

    double x1 = floor(xg - cw), x2 = ceil(xg + cw);
    double y1 = floor(yg - ch), y2 = ceil(yg + ch);
    if ((x1 < 0.0) || (x2 > 256.0)) {
        const double hw = fmin(256.0 - xg, xg);
        x1 = floor(xg - hw); x2 = ceil(xg + hw);
    }
    if ((y1 < 0.0) || (y2 > 256.0)) {
        const double hh = fmin(256.0 - yg, yg);
        y1 = floor(yg - hh); y2 = ceil(yg + hh);
    }

    const float mf = m ? 1.0f : 0.0f;
    rec[tid * 5 + 0] = mf * (float)sd;
    rec[tid * 5 + 1] = mf * (float)x1;
    rec[tid * 5 + 2] = mf * (float)y1;
    rec[tid * 5 + 3] = mf * (float)x2;
    rec[tid * 5 + 4] = mf * (float)y2;
    mout[i] = mf;
    __syncthreads();

    // coalesced write of the block's 1280-float out5 region (320 float4s)
    float4* dst = reinterpret_cast<float4*>(out5 + (size_t)blockIdx.x * 1280);
    const float4* src = reinterpret_cast<const float4*>(rec);
    dst[tid] = src[tid];
    if (tid < 64) dst[256 + tid] = src[256 + tid];
}

extern "C" void kernel_launch(void* const* d_in, const int* in_sizes, int n_in,
                              void* d_out, int out_size, void* d_ws, size_t ws_size,
                              hipStream_t stream) {
    // inputs: 0=mask(unused), 1=color, 2=w_bbx, 3=w_width, 4=w_height(dead), 5=w_score
    const float* color   = (const float*)d_in[1];
    const float* w_bbx   = (const float*)d_in[2];
    const float* w_width = (const float*)d_in[3];
    const float* w_score = (const float*)d_in[5];

    float* score_out = (float*)d_out;                       // 524288
    float* out5      = score_out + 524288;                  // 2621440
    float* mout      = score_out + 524288 + 2621440;        // 524288

    // ws layout: [lists 20480 f][wmap 524288 f]
    float* lists   = (float*)d_ws;
    float* wmap_ws = lists + 20480;

    k_main <<<2048, 256, 0, stream>>>(color, w_bbx, w_width, w_score, score_out, wmap_ws, lists);
    k_boxes<<<2048, 256, 0, stream>>>(score_out, wmap_ws, lists, out5, mout);
}